// Round 1
// baseline (322.514 us; speedup 1.0000x reference)
//
#include <hip/hip_runtime.h>
#include <hip/hip_bf16.h>

// Problem shape (fixed by reference):
//   Q,K: (4, 32, 8192, 128) fp32 ; rademacher: (128,) ; projection: (128, 64)
//   Outputs (concat, fp32): A_hat (4,128,128) | Q_bar (4,128,128) | K_bar (4,128,128)
#define BATCH   4
#define HEADS   32
#define NTOK    8192
#define DDIM    128
#define BLK     64          // token block size
#define NB      (NTOK/BLK)  // 128 token-blocks
#define SK      64          // sketch dim
#define OUT_A   0
#define OUT_QB  (BATCH*NB*NB)          // 65536
#define OUT_KB  (2*BATCH*NB*NB)        // 131072

// ---------------------------------------------------------------------------
// Kernel 1: head-mean + token-block-mean.  One block per (tensor, batch, nb).
// Reduces 32 heads x 64 tokens x 128 dims (1 MiB) -> 128 floats.
// ---------------------------------------------------------------------------
__global__ __launch_bounds__(256) void bar_reduce_kernel(
    const float* __restrict__ Q, const float* __restrict__ K,
    float* __restrict__ out)
{
    const int bid    = blockIdx.x;          // 0..1023
    const int tensor = bid >> 9;            // 0 = Q, 1 = K
    const int rem    = bid & 511;
    const int b      = rem >> 7;            // 0..3
    const int nb     = rem & 127;           // 0..127

    const float* base = tensor ? K : Q;
    const float* src  = base + ((size_t)b * HEADS * NTOK + (size_t)nb * BLK) * DDIM;

    const int tid  = threadIdx.x;
    const int lane = tid & 31;   // which float4 within a 128-dim row
    const int rgrp = tid >> 5;   // 0..7, which token row group

    float4 acc = make_float4(0.f, 0.f, 0.f, 0.f);
    #pragma unroll 4
    for (int h = 0; h < HEADS; ++h) {
        const float4* p = (const float4*)(src + (size_t)h * (NTOK * DDIM));
        #pragma unroll
        for (int t = rgrp; t < BLK; t += 8) {
            float4 v = p[t * 32 + lane];
            acc.x += v.x; acc.y += v.y; acc.z += v.z; acc.w += v.w;
        }
    }

    __shared__ float4 red[256];
    red[tid] = acc;
    __syncthreads();

    if (tid < 32) {
        float4 s = make_float4(0.f, 0.f, 0.f, 0.f);
        #pragma unroll
        for (int j = 0; j < 8; ++j) {
            float4 v = red[j * 32 + tid];
            s.x += v.x; s.y += v.y; s.z += v.z; s.w += v.w;
        }
        const float inv = 1.0f / (HEADS * BLK);   // 1/2048
        s.x *= inv; s.y *= inv; s.z *= inv; s.w *= inv;
        float* dst = out + (tensor ? OUT_KB : OUT_QB) + ((size_t)b * NB + nb) * DDIM;
        ((float4*)dst)[tid] = s;
    }
}

// ---------------------------------------------------------------------------
// Kernel 2a: tilde = (bar * rademacher) @ projection  -> d_ws
// One block per (tensor, batch): 8 blocks x 256 threads.
// Thread computes 32 outputs: row r = tid>>1, k in [(tid&1)*32, +32).
// ---------------------------------------------------------------------------
__global__ __launch_bounds__(256) void tilde_kernel(
    const float* __restrict__ out,          // contains Q_bar/K_bar already
    const float* __restrict__ radem,
    const float* __restrict__ proj,
    float* __restrict__ ws)
{
    const int bid    = blockIdx.x;          // 0..7
    const int tensor = bid >> 2;
    const int b      = bid & 3;

    const float* bar = out + (tensor ? OUT_KB : OUT_QB) + (size_t)b * (NB * DDIM);
    float* dst       = ws + (size_t)tensor * (BATCH * NB * SK) + (size_t)b * (NB * SK);

    const int tid = threadIdx.x;
    const int r   = tid >> 1;
    const int kb  = (tid & 1) * 32;

    float acc[32];
    #pragma unroll
    for (int j = 0; j < 32; ++j) acc[j] = 0.f;

    for (int d = 0; d < DDIM; ++d) {
        const float qv = bar[r * DDIM + d] * radem[d];
        const float* pr = proj + d * SK + kb;
        #pragma unroll
        for (int j = 0; j < 32; ++j) acc[j] += qv * pr[j];
    }
    #pragma unroll
    for (int j = 0; j < 32; ++j) dst[r * SK + kb + j] = acc[j];
}

// ---------------------------------------------------------------------------
// Kernel 2b: A_hat[b,q,s] = sum_k Qt[b,q,k]*Kt[b,s,k] / 8   -> d_out[0:65536]
// One block per batch: 4 blocks x 256 threads; thread does q = tid>>1,
// s in [(tid&1)*64, +64).
// ---------------------------------------------------------------------------
__global__ __launch_bounds__(256) void ahat_kernel(
    const float* __restrict__ ws, float* __restrict__ out)
{
    const int b   = blockIdx.x;
    const int tid = threadIdx.x;
    const int q   = tid >> 1;
    const int sb  = (tid & 1) * 64;

    const float* Qt = ws + (size_t)b * (NB * SK);
    const float* Kt = ws + (size_t)(BATCH * NB * SK) + (size_t)b * (NB * SK);

    float qrow[SK];
    #pragma unroll
    for (int k = 0; k < SK; ++k) qrow[k] = Qt[q * SK + k];

    for (int s = 0; s < 64; ++s) {
        const float* kr = Kt + (sb + s) * SK;
        float a = 0.f;
        #pragma unroll
        for (int k = 0; k < SK; ++k) a += qrow[k] * kr[k];
        out[(size_t)b * (NB * NB) + q * NB + sb + s] = a * 0.125f;
    }
}

extern "C" void kernel_launch(void* const* d_in, const int* in_sizes, int n_in,
                              void* d_out, int out_size, void* d_ws, size_t ws_size,
                              hipStream_t stream) {
    const float* Q     = (const float*)d_in[0];
    const float* K     = (const float*)d_in[1];
    const float* radem = (const float*)d_in[2];
    const float* proj  = (const float*)d_in[3];
    float* out = (float*)d_out;
    float* ws  = (float*)d_ws;   // needs 2*4*128*64 floats = 256 KiB

    bar_reduce_kernel<<<2 * BATCH * NB, 256, 0, stream>>>(Q, K, out);
    tilde_kernel<<<2 * BATCH, 256, 0, stream>>>(out, radem, proj, ws);
    ahat_kernel<<<BATCH, 256, 0, stream>>>(ws, out);
}

// Round 2
// 207.724 us; speedup vs baseline: 1.5526x; 1.5526x over previous
//
#include <hip/hip_runtime.h>
#include <hip/hip_bf16.h>

// Problem shape (fixed by reference):
//   Q,K: (4, 32, 8192, 128) fp32 ; rademacher: (128,) ; projection: (128, 64)
//   Outputs (concat, fp32): A_hat (4,128,128) | Q_bar (4,128,128) | K_bar (4,128,128)
#define BATCH   4
#define HEADS   32
#define NTOK    8192
#define DDIM    128
#define BLK     64          // token block size
#define NB      (NTOK/BLK)  // 128 token-blocks
#define SK      64          // sketch dim
#define OUT_QB  (BATCH*NB*NB)          // 65536
#define OUT_KB  (2*BATCH*NB*NB)        // 131072

// ---------------------------------------------------------------------------
// Kernel 1: head-mean + token-block-mean.  One block per (tensor, batch, nb).
// 1024 threads (16 waves) per block, 2 blocks/CU -> 32 waves/CU occupancy.
// Block reduces 32 heads x 64 tokens x 128 dims (1 MiB) -> 128 floats.
// Thread (lane = float4-col, tg = token-pair group): 32 heads x 2 tokens
// = 64 float4 loads, unroll-4 over heads -> 8 loads in flight.
// ---------------------------------------------------------------------------
__global__ __launch_bounds__(1024, 8) void bar_reduce_kernel(
    const float* __restrict__ Q, const float* __restrict__ K,
    float* __restrict__ out)
{
    const int bid    = blockIdx.x;          // 0..1023
    const int tensor = bid >> 9;            // 0 = Q, 1 = K
    const int rem    = bid & 511;
    const int b      = rem >> 7;            // 0..3
    const int nb     = rem & 127;           // 0..127

    const float* base = tensor ? K : Q;
    const float* src  = base + ((size_t)b * HEADS * NTOK + (size_t)nb * BLK) * DDIM;

    const int tid  = threadIdx.x;           // 0..1023
    const int lane = tid & 31;              // float4 col within 128-dim row
    const int tg   = tid >> 5;              // 0..31 -> tokens {2tg, 2tg+1}

    float4 acc = make_float4(0.f, 0.f, 0.f, 0.f);
    #pragma unroll 4
    for (int h = 0; h < HEADS; ++h) {
        const float4* p = (const float4*)(src + (size_t)h * (NTOK * DDIM));
        float4 v0 = p[(2 * tg    ) * 32 + lane];
        float4 v1 = p[(2 * tg + 1) * 32 + lane];
        acc.x += v0.x + v1.x;
        acc.y += v0.y + v1.y;
        acc.z += v0.z + v1.z;
        acc.w += v0.w + v1.w;
    }

    __shared__ float4 red[1024];            // 16 KiB
    red[tid] = acc;
    __syncthreads();

    #pragma unroll
    for (int s = 512; s >= 32; s >>= 1) {
        if (tid < s) {
            float4 a = red[tid], c = red[tid + s];
            a.x += c.x; a.y += c.y; a.z += c.z; a.w += c.w;
            red[tid] = a;
        }
        __syncthreads();
    }

    if (tid < 32) {
        float4 s = red[tid];
        const float inv = 1.0f / (HEADS * BLK);   // 1/2048
        s.x *= inv; s.y *= inv; s.z *= inv; s.w *= inv;
        float* dst = out + (tensor ? OUT_KB : OUT_QB) + ((size_t)b * NB + nb) * DDIM;
        ((float4*)dst)[tid] = s;
    }
}

// ---------------------------------------------------------------------------
// Kernel 2a: tilde = (bar * rademacher) @ projection  -> d_ws
// 32 blocks: (tensor, batch, quarter of 32 rows). Thread owns (row, 8 k's).
// All operands L2/L3-resident.
// ---------------------------------------------------------------------------
__global__ __launch_bounds__(256) void tilde_kernel(
    const float* __restrict__ out,          // contains Q_bar/K_bar already
    const float* __restrict__ radem,
    const float* __restrict__ proj,
    float* __restrict__ ws)
{
    const int bid     = blockIdx.x;         // 0..31
    const int tensor  = bid >> 4;
    const int b       = (bid >> 2) & 3;
    const int quarter = bid & 3;

    const float* bar = out + (tensor ? OUT_KB : OUT_QB)
                     + (size_t)b * (NB * DDIM) + (size_t)quarter * 32 * DDIM;
    float* dst       = ws + (size_t)tensor * (BATCH * NB * SK)
                     + (size_t)b * (NB * SK) + (size_t)quarter * 32 * SK;

    const int tid = threadIdx.x;
    const int r   = tid >> 3;               // 0..31 local row
    const int kg  = (tid & 7) * 8;          // k base

    float acc[8];
    #pragma unroll
    for (int j = 0; j < 8; ++j) acc[j] = 0.f;

    #pragma unroll 4
    for (int d = 0; d < DDIM; ++d) {
        const float qv = bar[r * DDIM + d] * radem[d];
        const float4* pr = (const float4*)(proj + d * SK + kg);
        float4 p0 = pr[0], p1 = pr[1];
        acc[0] += qv * p0.x; acc[1] += qv * p0.y;
        acc[2] += qv * p0.z; acc[3] += qv * p0.w;
        acc[4] += qv * p1.x; acc[5] += qv * p1.y;
        acc[6] += qv * p1.z; acc[7] += qv * p1.w;
    }

    float4* dp = (float4*)(dst + r * SK + kg);
    dp[0] = make_float4(acc[0], acc[1], acc[2], acc[3]);
    dp[1] = make_float4(acc[4], acc[5], acc[6], acc[7]);
}

// ---------------------------------------------------------------------------
// Kernel 2b: A_hat[b,q,s] = sum_k Qt[b,q,k]*Kt[b,s,k] / 8   -> d_out[0:65536]
// 64 blocks: (batch, q-group of 8). Thread owns (q, 4 s's). L2-resident.
// ---------------------------------------------------------------------------
__global__ __launch_bounds__(256) void ahat_kernel(
    const float* __restrict__ ws, float* __restrict__ out)
{
    const int bid = blockIdx.x;             // 0..63
    const int b   = bid >> 4;
    const int qg  = bid & 15;

    const float* Qt = ws + (size_t)b * (NB * SK);
    const float* Kt = ws + (size_t)(BATCH * NB * SK) + (size_t)b * (NB * SK);

    const int tid = threadIdx.x;
    const int q   = qg * 8 + (tid >> 5);
    const int s0  = tid & 31;

    float4 qr[16];
    const float4* qp = (const float4*)(Qt + q * SK);
    #pragma unroll
    for (int i = 0; i < 16; ++i) qr[i] = qp[i];

    #pragma unroll
    for (int m = 0; m < 4; ++m) {
        const int s = s0 + m * 32;
        const float4* kp = (const float4*)(Kt + s * SK);
        float a = 0.f;
        #pragma unroll
        for (int i = 0; i < 16; ++i) {
            float4 kv = kp[i];
            a += qr[i].x * kv.x + qr[i].y * kv.y + qr[i].z * kv.z + qr[i].w * kv.w;
        }
        out[(size_t)b * (NB * NB) + q * NB + s] = a * 0.125f;
    }
}

extern "C" void kernel_launch(void* const* d_in, const int* in_sizes, int n_in,
                              void* d_out, int out_size, void* d_ws, size_t ws_size,
                              hipStream_t stream) {
    const float* Q     = (const float*)d_in[0];
    const float* K     = (const float*)d_in[1];
    const float* radem = (const float*)d_in[2];
    const float* proj  = (const float*)d_in[3];
    float* out = (float*)d_out;
    float* ws  = (float*)d_ws;   // needs 2*4*128*64 floats = 256 KiB

    bar_reduce_kernel<<<2 * BATCH * NB, 1024, 0, stream>>>(Q, K, out);
    tilde_kernel<<<32, 256, 0, stream>>>(out, radem, proj, ws);
    ahat_kernel<<<64, 256, 0, stream>>>(ws, out);
}

// Round 4
// 172.220 us; speedup vs baseline: 1.8727x; 1.2062x over previous
//
#include <hip/hip_runtime.h>
#include <hip/hip_bf16.h>

// Problem shape (fixed by reference):
//   Q,K: (4, 32, 8192, 128) fp32 ; rademacher: (128,) ; projection: (128, 64)
//   Outputs (concat, fp32): A_hat (4,128,128) | Q_bar (4,128,128) | K_bar (4,128,128)
#define BATCH   4
#define HEADS   32
#define NTOK    8192
#define DDIM    128
#define BLK     64          // token block size
#define NB      (NTOK/BLK)  // 128 token-blocks
#define SK      64          // sketch dim
#define OUT_QB  (BATCH*NB*NB)          // 65536
#define OUT_KB  (2*BATCH*NB*NB)        // 131072

typedef float v4f __attribute__((ext_vector_type(4)));  // nontemporal-compatible

// ---------------------------------------------------------------------------
// Kernel 1: head-mean + token-block-mean + fused tilde tail.
// One block per (tensor, batch, nb); 1024 threads (16 waves), 2 blocks/CU.
// Streams 32 heads x 64 tokens x 128 dims (1 MiB) with non-temporal v4f
// loads -> bar (128 floats) -> out, and tilde row (64 floats) -> ws.
// ---------------------------------------------------------------------------
__global__ __launch_bounds__(1024, 8) void bar_reduce_kernel(
    const float* __restrict__ Q, const float* __restrict__ K,
    const float* __restrict__ radem, const float* __restrict__ proj,
    float* __restrict__ out, float* __restrict__ ws)
{
    const int bid    = blockIdx.x;          // 0..1023
    const int tensor = bid >> 9;            // 0 = Q, 1 = K
    const int rem    = bid & 511;
    const int b      = rem >> 7;            // 0..3
    const int nb     = rem & 127;           // 0..127

    const float* base = tensor ? K : Q;
    const float* src  = base + ((size_t)b * HEADS * NTOK + (size_t)nb * BLK) * DDIM;

    const int tid  = threadIdx.x;           // 0..1023
    const int lane = tid & 31;              // v4f col within 128-dim row
    const int tg   = tid >> 5;              // 0..31 -> tokens {2tg, 2tg+1}

    v4f acc0 = {0.f, 0.f, 0.f, 0.f};
    v4f acc1 = {0.f, 0.f, 0.f, 0.f};
    #pragma unroll 4
    for (int h = 0; h < HEADS; ++h) {
        const v4f* p = (const v4f*)(src + (size_t)h * (NTOK * DDIM));
        v4f v0 = __builtin_nontemporal_load(&p[(2 * tg    ) * 32 + lane]);
        v4f v1 = __builtin_nontemporal_load(&p[(2 * tg + 1) * 32 + lane]);
        acc0 += v0;
        acc1 += v1;
    }
    v4f acc = acc0 + acc1;

    __shared__ v4f   red[1024];             // 16 KiB
    __shared__ float barS[DDIM];            // bar * radem, for the tilde tail
    red[tid] = acc;
    __syncthreads();

    #pragma unroll
    for (int s = 512; s >= 32; s >>= 1) {
        if (tid < s) {
            red[tid] += red[tid + s];
        }
        __syncthreads();
    }

    if (tid < 32) {
        v4f s = red[tid];
        const float inv = 1.0f / (HEADS * BLK);   // 1/2048
        s *= inv;
        float* dst = out + (tensor ? OUT_KB : OUT_QB) + ((size_t)b * NB + nb) * DDIM;
        ((v4f*)dst)[tid] = s;
        v4f rd = ((const v4f*)radem)[tid];
        v4f sr = s * rd;
        barS[4 * tid + 0] = sr.x;
        barS[4 * tid + 1] = sr.y;
        barS[4 * tid + 2] = sr.z;
        barS[4 * tid + 3] = sr.w;
    }
    __syncthreads();

    // tilde tail: tilde[nb][k] = sum_d barS[d] * proj[d][k], k = 0..63
    if (tid < SK) {
        const int k = tid;
        float a0 = 0.f, a1 = 0.f, a2 = 0.f, a3 = 0.f;
        #pragma unroll 8
        for (int d = 0; d < DDIM; d += 4) {
            a0 += barS[d + 0] * proj[(d + 0) * SK + k];
            a1 += barS[d + 1] * proj[(d + 1) * SK + k];
            a2 += barS[d + 2] * proj[(d + 2) * SK + k];
            a3 += barS[d + 3] * proj[(d + 3) * SK + k];
        }
        ws[((size_t)tensor * BATCH + b) * (NB * SK) + (size_t)nb * SK + k]
            = (a0 + a1) + (a2 + a3);
    }
}

// ---------------------------------------------------------------------------
// Kernel 2: A_hat[b,q,s] = sum_k Qt[b,q,k]*Kt[b,s,k] / 8   -> d_out[0:65536]
// 64 blocks: (batch, q-group of 8). Thread owns (q, 4 s's). L2-resident.
// ---------------------------------------------------------------------------
__global__ __launch_bounds__(256) void ahat_kernel(
    const float* __restrict__ ws, float* __restrict__ out)
{
    const int bid = blockIdx.x;             // 0..63
    const int b   = bid >> 4;
    const int qg  = bid & 15;

    const float* Qt = ws + (size_t)b * (NB * SK);
    const float* Kt = ws + (size_t)(BATCH * NB * SK) + (size_t)b * (NB * SK);

    const int tid = threadIdx.x;
    const int q   = qg * 8 + (tid >> 5);
    const int s0  = tid & 31;

    float4 qr[16];
    const float4* qp = (const float4*)(Qt + q * SK);
    #pragma unroll
    for (int i = 0; i < 16; ++i) qr[i] = qp[i];

    #pragma unroll
    for (int m = 0; m < 4; ++m) {
        const int s = s0 + m * 32;
        const float4* kp = (const float4*)(Kt + s * SK);
        float a = 0.f;
        #pragma unroll
        for (int i = 0; i < 16; ++i) {
            float4 kv = kp[i];
            a += qr[i].x * kv.x + qr[i].y * kv.y + qr[i].z * kv.z + qr[i].w * kv.w;
        }
        out[(size_t)b * (NB * NB) + q * NB + s] = a * 0.125f;
    }
}

extern "C" void kernel_launch(void* const* d_in, const int* in_sizes, int n_in,
                              void* d_out, int out_size, void* d_ws, size_t ws_size,
                              hipStream_t stream) {
    const float* Q     = (const float*)d_in[0];
    const float* K     = (const float*)d_in[1];
    const float* radem = (const float*)d_in[2];
    const float* proj  = (const float*)d_in[3];
    float* out = (float*)d_out;
    float* ws  = (float*)d_ws;   // needs 2*4*128*64 floats = 256 KiB

    bar_reduce_kernel<<<2 * BATCH * NB, 1024, 0, stream>>>(Q, K, radem, proj, out, ws);
    ahat_kernel<<<BATCH * 16, 256, 0, stream>>>(ws, out);
}